// Round 2
// baseline (161.878 us; speedup 1.0000x reference)
//
#include <hip/hip_runtime.h>
#include <hip/hip_bf16.h>

// QuantisedMonDEQ: n=512, d=784, B=128, C=10. All inputs/outputs float32.
// z_{t+1} = relu(0.5 z + 0.5 (Wq z + Ux)), 40 iters; logits = z*^T Wc^T + bc.
//
// INT8 formulation: Wq = sW*Q, Q = rint(W/sW) exact int8. z held as Q4.11
// fixed point v (int16), split v = 256*zh + (zlm+128), zh,zlm int8.
//   Q.v = 256*(Q.zh) + Q.zlm + 128*rowsum(Q)   (rowsum folded into Ux).
// Iters 1..27: hi-plane only; iters 28..39 both planes. Z (= 2048*z, fp32,
// bit-exact power-of-two scaling of the original) + Ux fold live in registers
// per lane; LDS carries only the int8 B-plane transpose. Rowsum via
// ones-vector i8 MFMA. Pack: v_cvt_pk_i16_i32 (saturating) + v_perm_b32.
//
// Two dispatches: (1) persistent prep = maxabs phase (512-block grid-stride +
// atomicMax + device-scope counter spin; 512 blocks = exactly 2/CU at 55.8KB
// LDS -> co-residency guaranteed) then quantW / UxT phase. (2) solve with
// 1024-thread blocks (16 waves, MT=2): 4 waves/SIMD hides the dependent-MFMA
// + epilogue latency that 2 waves/SIMD left ~20% idle.

#define N_DIM 512
#define D_DIM 784
#define B_DIM 128
#define C_DIM 10
#define QMAX 127.0f
#define N_ITERS 40
#define HILO_START 28
#define ZPITCH 528     // bytes per column plane row; 16B-aligned
#define MT 2           // 16-row M-tiles per wave (16 waves x 32 rows = 512)
#define UPITCH 808     // bf16 elems per staged x row (800 data+pad), 16B-aligned

typedef int    i32x4  __attribute__((ext_vector_type(4)));
typedef float  f32x4  __attribute__((ext_vector_type(4)));
typedef __bf16 bf16x8 __attribute__((ext_vector_type(8)));
typedef short  s16x2  __attribute__((ext_vector_type(2)));

// vq[0..3] (>=0) -> saturate to i16, h = hi bytes, l = lo bytes ^ 0x80.
__device__ __forceinline__ void pack_hl(const int vq[4], unsigned int& h, unsigned int& l) {
    int pk01, pk23;
#if __has_builtin(__builtin_amdgcn_cvt_pk_i16)
    union { s16x2 v; int i; } u0, u1;
    u0.v = __builtin_amdgcn_cvt_pk_i16(vq[0], vq[1]);
    u1.v = __builtin_amdgcn_cvt_pk_i16(vq[2], vq[3]);
    pk01 = u0.i; pk23 = u1.i;
#else
    asm("v_cvt_pk_i16_i32 %0, %1, %2" : "=v"(pk01) : "v"(vq[0]), "v"(vq[1]));
    asm("v_cvt_pk_i16_i32 %0, %1, %2" : "=v"(pk23) : "v"(vq[2]), "v"(vq[3]));
#endif
    h = __builtin_amdgcn_perm((unsigned int)pk23, (unsigned int)pk01, 0x07050301u);
    l = __builtin_amdgcn_perm((unsigned int)pk23, (unsigned int)pk01, 0x06040200u) ^ 0x80808080u;
}

// ---- persistent prep: phase1 maxabs(all blocks) -> spin -> phase2 quant ----
// sync layout (int32): [0]=arrival counter, [1]=maxW bits, [2]=maxU bits,
// [3]=maxb bits. Host memsets these 16 bytes to 0 before each launch.
__global__ __launch_bounds__(256) void prep_kernel(const float* __restrict__ W,
                                                   const float* __restrict__ U,
                                                   const float* __restrict__ b,
                                                   const float* __restrict__ x,
                                                   int* __restrict__ sync,
                                                   signed char* __restrict__ Qp8,
                                                   float* __restrict__ UxT) {
    __shared__ __bf16 xhS[16][UPITCH];
    __shared__ __bf16 xlS[16][UPITCH];
    __shared__ f32x4  sacc[4][64];
    __shared__ float  smax[3];
    const int t = threadIdx.x;
    const int wave = t >> 6, lane = t & 63;

    // ---------- phase 1: global max|.| over W, U, b ----------
    {
        const int gid = blockIdx.x * 256 + t;    // 0..131071 (>= each region)
        float mW = 0.0f, mU = 0.0f, mB = 0.0f;
        if (gid < N_DIM * N_DIM / 4) {
            float4 v = ((const float4*)W)[gid];
            mW = fmaxf(fmaxf(fabsf(v.x), fabsf(v.y)), fmaxf(fabsf(v.z), fabsf(v.w)));
        }
        if (gid < N_DIM * D_DIM / 4) {
            float4 v = ((const float4*)U)[gid];
            mU = fmaxf(fmaxf(fabsf(v.x), fabsf(v.y)), fmaxf(fabsf(v.z), fabsf(v.w)));
        }
        if (gid < N_DIM / 4) {
            float4 v = ((const float4*)b)[gid];
            mB = fmaxf(fmaxf(fabsf(v.x), fabsf(v.y)), fmaxf(fabsf(v.z), fabsf(v.w)));
        }
#pragma unroll
        for (int s = 1; s < 64; s <<= 1) {
            mW = fmaxf(mW, __shfl_xor(mW, s));
            mU = fmaxf(mU, __shfl_xor(mU, s));
            mB = fmaxf(mB, __shfl_xor(mB, s));
        }
        float* ls = (float*)sacc;
        if (lane == 0) { ls[wave * 3 + 0] = mW; ls[wave * 3 + 1] = mU; ls[wave * 3 + 2] = mB; }
        __syncthreads();
        if (t == 0) {
            float aW = fmaxf(fmaxf(ls[0], ls[3]), fmaxf(ls[6], ls[9]));
            float aU = fmaxf(fmaxf(ls[1], ls[4]), fmaxf(ls[7], ls[10]));
            float aB = fmaxf(fmaxf(ls[2], ls[5]), fmaxf(ls[8], ls[11]));
            atomicMax(&sync[1], __float_as_int(aW));   // >=0 floats: int-monotone
            atomicMax(&sync[2], __float_as_int(aU));
            atomicMax(&sync[3], __float_as_int(aB));
            __hip_atomic_fetch_add(&sync[0], 1, __ATOMIC_ACQ_REL, __HIP_MEMORY_SCOPE_AGENT);
            while (__hip_atomic_load(&sync[0], __ATOMIC_ACQUIRE, __HIP_MEMORY_SCOPE_AGENT)
                   < (int)gridDim.x)
                __builtin_amdgcn_s_sleep(2);
            smax[0] = __int_as_float(__hip_atomic_load(&sync[1], __ATOMIC_RELAXED, __HIP_MEMORY_SCOPE_AGENT));
            smax[1] = __int_as_float(__hip_atomic_load(&sync[2], __ATOMIC_RELAXED, __HIP_MEMORY_SCOPE_AGENT));
            smax[2] = __int_as_float(__hip_atomic_load(&sync[3], __ATOMIC_RELAXED, __HIP_MEMORY_SCOPE_AGENT));
        }
        __syncthreads();
    }

    // ---------- phase 2 ----------
    if (blockIdx.x < 256) {
        // ---- W quant (2 rows per block) ----
        const float s = smax[0] * (1.0f / QMAX);
        const float inv = 1.0f / s;
        int idx = blockIdx.x * 256 + t;            // float4 index into W
        float4 w = ((const float4*)W)[idx];
        int k = (idx << 2) & (N_DIM - 1);
        int r = (idx << 2) >> 9;
        char4 c;
        c.x = (signed char)(int)rintf(w.x * inv);
        c.y = (signed char)(int)rintf(w.y * inv);
        c.z = (signed char)(int)rintf(w.z * inv);
        c.w = (signed char)(int)rintf(w.w * inv);
        int kc = k >> 6, q = (k >> 4) & 3, jj = k & 15;
        *(char4*)&Qp8[((kc << 9) + r) * 64 + q * 16 + jj] = c;
    } else {
        // ---- UxT[c][i] = bq[i] + sU * sum_d Qu[i][d]*x[c][d] ----
        const float sU = smax[1] * (1.0f / QMAX);
        const float invU = 1.0f / sU;
        const float sb = smax[2] * (1.0f / QMAX);
        const int bx = blockIdx.x - 256;           // 0..255
        const int i0 = (bx >> 3) * 16;             // U-row tile base (32 groups)
        const int c0 = (bx & 7) * 16;              // batch-col tile base (8 groups)
        // vectorized x staging: hi/lo bf16 split, float4 loads
        for (int i = t; i < 16 * 196; i += 256) {
            int r = i / 196, kf = i - r * 196;
            float4 v = *(const float4*)&x[(c0 + r) * D_DIM + (kf << 2)];
            union { __bf16 e[4]; ushort4 u; } hh, ll;
            float f0 = v.x, f1 = v.y, f2 = v.z, f3 = v.w;
            __bf16 h0 = (__bf16)f0, h1 = (__bf16)f1, h2 = (__bf16)f2, h3 = (__bf16)f3;
            hh.e[0] = h0; hh.e[1] = h1; hh.e[2] = h2; hh.e[3] = h3;
            ll.e[0] = (__bf16)(f0 - (float)h0);
            ll.e[1] = (__bf16)(f1 - (float)h1);
            ll.e[2] = (__bf16)(f2 - (float)h2);
            ll.e[3] = (__bf16)(f3 - (float)h3);
            *(ushort4*)&xhS[r][kf << 2] = hh.u;
            *(ushort4*)&xlS[r][kf << 2] = ll.u;
        }
        // zero-fill pad k in [784, 800)
        {
            int r = t >> 4, k = D_DIM + (t & 15);
            xhS[r][k] = (__bf16)0.0f; xlS[r][k] = (__bf16)0.0f;
        }
        __syncthreads();
        const int m = lane & 15, quad = lane >> 4;
        f32x4 acc = {};
        for (int kc = wave; kc < 25; kc += 4) {
            const int k0 = (kc << 5) + (quad << 3);
            bf16x8 au = {};
            if (k0 < D_DIM) {   // kc==24 only quads 0,1 valid (784 = 24*32+16)
                const float4 u0 = *(const float4*)&U[(i0 + m) * D_DIM + k0];
                const float4 u1 = *(const float4*)&U[(i0 + m) * D_DIM + k0 + 4];
                au[0] = (__bf16)rintf(u0.x * invU); au[1] = (__bf16)rintf(u0.y * invU);
                au[2] = (__bf16)rintf(u0.z * invU); au[3] = (__bf16)rintf(u0.w * invU);
                au[4] = (__bf16)rintf(u1.x * invU); au[5] = (__bf16)rintf(u1.y * invU);
                au[6] = (__bf16)rintf(u1.z * invU); au[7] = (__bf16)rintf(u1.w * invU);
            }
            bf16x8 bh = *(const bf16x8*)&xhS[m][k0];
            bf16x8 bl = *(const bf16x8*)&xlS[m][k0];
            acc = __builtin_amdgcn_mfma_f32_16x16x32_bf16(au, bh, acc, 0, 0, 0);
            acc = __builtin_amdgcn_mfma_f32_16x16x32_bf16(au, bl, acc, 0, 0, 0);
        }
        sacc[wave][lane] = acc;
        __syncthreads();
        if (wave == 0) {
            f32x4 s0 = sacc[0][lane], s1 = sacc[1][lane];
            f32x4 s2 = sacc[2][lane], s3 = sacc[3][lane];
            const int row0 = i0 + (quad << 2);
            f32x4 o;
#pragma unroll
            for (int r = 0; r < 4; ++r)
                o[r] = sU * (s0[r] + s1[r] + s2[r] + s3[r])
                     + rintf(b[row0 + r] / sb) * sb;
            *(f32x4*)&UxT[(c0 + m) * N_DIM + row0] = o;
        }
    }
}

// ---------------- fused int8-MFMA solve + logits (16 waves) ----------------
__global__ __launch_bounds__(1024, 1) void solve_kernel(const signed char* __restrict__ Qp8,
                                                        const float* __restrict__ UxT,
                                                        const float* __restrict__ wsf,
                                                        const float* __restrict__ Wc,
                                                        const float* __restrict__ bc,
                                                        float* __restrict__ out) {
    __shared__ signed char zh[2][16][ZPITCH];
    __shared__ signed char zl[2][16][ZPITCH];
    __shared__ float red[16][16][C_DIM];
    const int t = threadIdx.x;
    const int wave = t >> 6;      // 0..15
    const int lane = t & 63;
    const int m = lane & 15;      // batch col within block tile
    const int quad = lane >> 4;   // D-row group
    const int c0 = blockIdx.x * 16;
    const float sW = wsf[1] * (1.0f / QMAX);   // maxW bits written by prep
    const float c1 = sW * (1.0f / 2048.0f);
    const float hc_hi = c1 * 128.0f;     // original-units constants
    const float g_hi = sW * 128.0f;      // = hc_hi * 2048 (exact)
    const float g_lo = sW * 0.5f;        // = hc_lo * 2048 (exact)
    const int rowbase = wave * 32;

    // register-resident A fragments: 8 kc x 2 M-tiles x 16B
    i32x4 A[MT][8];
#pragma unroll
    for (int ti = 0; ti < MT; ++ti)
#pragma unroll
        for (int kc = 0; kc < 8; ++kc)
            A[ti][kc] = *(const i32x4*)&Qp8[((kc << 9) + rowbase + ti * 16 + m) * 64 + (quad << 4)];

    // rowsum(Q) per row via ones-vector i8 MFMA (exact int; layout matches C)
    const i32x4 onesb = {0x01010101, 0x01010101, 0x01010101, 0x01010101};
    i32x4 rs[MT];
#pragma unroll
    for (int ti = 0; ti < MT; ++ti) {
        i32x4 a = {};
#pragma unroll
        for (int kc = 0; kc < 8; ++kc)
            a = __builtin_amdgcn_mfma_i32_16x16x64_i8(A[ti][kc], onesb, a, 0, 0, 0);
        rs[ti] = a;
    }

    // prologue. Scaled units: Z = 2048*z (exact 2^11 scaling, bit-identical
    // trajectory), UX2 = 2048*uxh.
    float Z[MT][4];
    float UX2[MT][4];
#pragma unroll
    for (int ti = 0; ti < MT; ++ti) {
        const int row0 = rowbase + ti * 16 + (quad << 2);
        const f32x4 v4 = *(const f32x4*)&UxT[(c0 + m) * N_DIM + row0];
        int vq[4];
#pragma unroll
        for (int r = 0; r < 4; ++r) {
            const float v = v4[r];
            const float uxh = 0.5f * (v + hc_hi * (float)rs[ti][r]);
            UX2[ti][r] = uxh * 2048.0f;
            const float z1 = fmaxf(0.5f * v, 0.0f);
            const float Z1 = z1 * 2048.0f;
            Z[ti][r] = Z1;
            vq[r] = (int)rintf(Z1);
        }
        unsigned int h, l;
        pack_hl(vq, h, l);
        *(unsigned int*)&zh[0][m][row0] = h;
        *(unsigned int*)&zl[0][m][row0] = l;
    }

#pragma unroll
    for (int ti = 0; ti < MT; ++ti)
#pragma unroll
        for (int kc = 0; kc < 8; ++kc)
            asm volatile("" : "+v"(A[ti][kc]));
    __syncthreads();

    int cur = 0;
    for (int it = 1; it < N_ITERS; ++it) {
        const bool lo = (it >= HILO_START);
        const bool wlo = (it >= HILO_START - 1);
        i32x4 acch[MT] = {};
        i32x4 accl[MT] = {};
        if (lo) {
#pragma unroll
            for (int kc = 0; kc < 8; ++kc) {
                i32x4 bh = *(const i32x4*)&zh[cur][m][(kc << 6) + (quad << 4)];
                i32x4 bl = *(const i32x4*)&zl[cur][m][(kc << 6) + (quad << 4)];
#pragma unroll
                for (int ti = 0; ti < MT; ++ti) {
                    acch[ti] = __builtin_amdgcn_mfma_i32_16x16x64_i8(A[ti][kc], bh, acch[ti], 0, 0, 0);
                    accl[ti] = __builtin_amdgcn_mfma_i32_16x16x64_i8(A[ti][kc], bl, accl[ti], 0, 0, 0);
                }
            }
        } else {
#pragma unroll
            for (int kc = 0; kc < 8; ++kc) {
                i32x4 bh = *(const i32x4*)&zh[cur][m][(kc << 6) + (quad << 4)];
#pragma unroll
                for (int ti = 0; ti < MT; ++ti)
                    acch[ti] = __builtin_amdgcn_mfma_i32_16x16x64_i8(A[ti][kc], bh, acch[ti], 0, 0, 0);
            }
        }
        const int nxt = cur ^ 1;
#pragma unroll
        for (int ti = 0; ti < MT; ++ti) {
            const int row0 = rowbase + ti * 16 + (quad << 2);
            int vq[4];
#pragma unroll
            for (int r = 0; r < 4; ++r) {
                float base = fmaf(0.5f, Z[ti][r], UX2[ti][r]);
                float u = lo ? fmaf(g_hi, (float)acch[ti][r], fmaf(g_lo, (float)accl[ti][r], base))
                             : fmaf(g_hi, (float)acch[ti][r], base);
                float Zn = fmaxf(u, 0.0f);
                Z[ti][r] = Zn;
                vq[r] = (int)rintf(Zn);
            }
            unsigned int h, l;
            pack_hl(vq, h, l);
            *(unsigned int*)&zh[nxt][m][row0] = h;
            if (wlo) *(unsigned int*)&zl[nxt][m][row0] = l;
        }
        __syncthreads();
        cur = nxt;
    }

    // ---- fused logits from register z (shfl-first reduction) ----
    {
        float p[C_DIM];
#pragma unroll
        for (int cl = 0; cl < C_DIM; ++cl) p[cl] = 0.0f;
#pragma unroll
        for (int ti = 0; ti < MT; ++ti) {
            const int row0 = rowbase + ti * 16 + (quad << 2);
#pragma unroll
            for (int r = 0; r < 4; ++r) {
                float zv = Z[ti][r] * (1.0f / 2048.0f);
#pragma unroll
                for (int cl = 0; cl < C_DIM; ++cl)
                    p[cl] += zv * Wc[cl * N_DIM + row0 + r];
            }
        }
#pragma unroll
        for (int cl = 0; cl < C_DIM; ++cl) {
            p[cl] += __shfl_xor(p[cl], 16);
            p[cl] += __shfl_xor(p[cl], 32);
        }
        if (lane < 16) {
#pragma unroll
            for (int cl = 0; cl < C_DIM; ++cl) red[wave][lane][cl] = p[cl];
        }
        __syncthreads();
        for (int s = 8; s > 0; s >>= 1) {
            if (wave < s && lane < 16) {
#pragma unroll
                for (int cl = 0; cl < C_DIM; ++cl)
                    red[wave][lane][cl] += red[wave + s][lane][cl];
            }
            __syncthreads();
        }
        if (t < 16 * C_DIM) {
            int col = t & 15;
            int cl  = t >> 4;
            out[(c0 + col) * C_DIM + cl] = red[0][col][cl] + bc[cl];
        }
    }
}

extern "C" void kernel_launch(void* const* d_in, const int* in_sizes, int n_in,
                              void* d_out, int out_size, void* d_ws, size_t ws_size,
                              hipStream_t stream) {
    const float* W  = (const float*)d_in[0];
    const float* U  = (const float*)d_in[1];
    const float* b  = (const float*)d_in[2];
    const float* x  = (const float*)d_in[3];
    const float* Wc = (const float*)d_in[4];
    const float* bc = (const float*)d_in[5];
    float* out = (float*)d_out;

    float* ws = (float*)d_ws;
    int* sync = (int*)ws;                               // [0]=cnt [1..3]=max bits
    signed char* Qp8 = (signed char*)(ws + 256);        // 512x512 int8, [kc][r][64B]
    float* UxT = ws + 256 + (N_DIM * N_DIM / 4);        // 128x512 fp32

    hipMemsetAsync(sync, 0, 16, stream);
    prep_kernel<<<512, 256, 0, stream>>>(W, U, b, x, sync, Qp8, UxT);
    solve_kernel<<<8, 1024, 0, stream>>>(Qp8, UxT, ws, Wc, bc, out);
}

// Round 3
// 154.821 us; speedup vs baseline: 1.0456x; 1.0456x over previous
//
#include <hip/hip_runtime.h>
#include <hip/hip_bf16.h>

// QuantisedMonDEQ: n=512, d=784, B=128, C=10. All inputs/outputs float32.
// z_{t+1} = relu(0.5 z + 0.5 (Wq z + Ux)), 40 iters; logits = z*^T Wc^T + bc.
//
// INT8 formulation: Wq = sW*Q, Q = rint(W/sW) exact int8. z held as Q4.11
// fixed point v (int16), split v = 256*zh + (zlm+128), zh,zlm int8.
//   Q.v = 256*(Q.zh) + Q.zlm + 128*rowsum(Q)   (rowsum folded into Ux).
// Iters 1..27: hi-plane only; iters 28..39 both planes. Z (= 2048*z, fp32,
// bit-exact power-of-two scaling) + Ux fold live in registers per lane; LDS
// carries only the int8 B-plane transpose. Rowsum via ones-vector i8 MFMA.
// Pack: v_cvt_pk_i16_i32 (saturating) + v_perm_b32.
//
// Sync redesign (round 2 post-mortem): the fused prep's global barrier did
// 2048 contended RMWs on ONE cacheline (3 atomicMax + 1 add x 512 blocks)
// ~= the observed 60us. Now: 129 producer blocks (64 W / 64 U / 1 b) each do
// one partial store + one fetch_add(RELEASE) to a PER-REGION counter on its
// own cacheline (129 RMWs over 3 lines); consumers poll read-only (ACQUIRE)
// and reduce the 64 partials locally. W-quant blocks wait only on cntW;
// UxT blocks on cntU+cntB. Produce-before-poll => deadlock-free regardless
// of residency (512 blocks @ 56KB LDS = exactly 2/CU anyway).

#define N_DIM 512
#define D_DIM 784
#define B_DIM 128
#define C_DIM 10
#define QMAX 127.0f
#define N_ITERS 40
#define HILO_START 28
#define ZPITCH 528     // bytes per column plane row; 16B-aligned
#define MT 2           // 16-row M-tiles per wave (16 waves x 32 rows = 512)
#define UPITCH 808     // bf16 elems per staged x row (800 data+pad), 16B-aligned

typedef int    i32x4  __attribute__((ext_vector_type(4)));
typedef float  f32x4  __attribute__((ext_vector_type(4)));
typedef __bf16 bf16x8 __attribute__((ext_vector_type(8)));
typedef short  s16x2  __attribute__((ext_vector_type(2)));

// ws int-layout: [0]=cntW, [32]=cntU, [64]=cntB (separate 128B lines),
// [72..74]=final maxes (floats), [80..143]=pW, [144..207]=pU, [208]=pB.
// Host memsets bytes [0,320) each replay (counters+finals; partials are
// fully rewritten before the RELEASE each replay).
#define WS_CNTW 0
#define WS_CNTU 32
#define WS_CNTB 64
#define WS_FIN  72
#define WS_PW   80
#define WS_PU   144
#define WS_PB   208

// vq[0..3] (>=0) -> saturate to i16, h = hi bytes, l = lo bytes ^ 0x80.
__device__ __forceinline__ void pack_hl(const int vq[4], unsigned int& h, unsigned int& l) {
    int pk01, pk23;
#if __has_builtin(__builtin_amdgcn_cvt_pk_i16)
    union { s16x2 v; int i; } u0, u1;
    u0.v = __builtin_amdgcn_cvt_pk_i16(vq[0], vq[1]);
    u1.v = __builtin_amdgcn_cvt_pk_i16(vq[2], vq[3]);
    pk01 = u0.i; pk23 = u1.i;
#else
    asm("v_cvt_pk_i16_i32 %0, %1, %2" : "=v"(pk01) : "v"(vq[0]), "v"(vq[1]));
    asm("v_cvt_pk_i16_i32 %0, %1, %2" : "=v"(pk23) : "v"(vq[2]), "v"(vq[3]));
#endif
    h = __builtin_amdgcn_perm((unsigned int)pk23, (unsigned int)pk01, 0x07050301u);
    l = __builtin_amdgcn_perm((unsigned int)pk23, (unsigned int)pk01, 0x06040200u) ^ 0x80808080u;
}

// ---- persistent prep: phase1 maxabs (129 producer blocks) -> low-contention
// ---- region barrier -> phase2 quantW / UxT ----
__global__ __launch_bounds__(256) void prep_kernel(const float* __restrict__ W,
                                                   const float* __restrict__ U,
                                                   const float* __restrict__ b,
                                                   const float* __restrict__ x,
                                                   int* __restrict__ sync,
                                                   signed char* __restrict__ Qp8,
                                                   float* __restrict__ UxT) {
    __shared__ __bf16 xhS[16][UPITCH];
    __shared__ __bf16 xlS[16][UPITCH];
    __shared__ f32x4  sacc[4][64];
    __shared__ float  smax[3];
    const int t = threadIdx.x;
    const int wave = t >> 6, lane = t & 63;
    const int bid = blockIdx.x;

    int*   cntW = &sync[WS_CNTW];
    int*   cntU = &sync[WS_CNTU];
    int*   cntB = &sync[WS_CNTB];
    float* fin  = (float*)&sync[WS_FIN];
    float* pW   = (float*)&sync[WS_PW];
    float* pU   = (float*)&sync[WS_PU];
    float* pB   = (float*)&sync[WS_PB];

    // ---------- phase 1: producers (blocks 0..128) ----------
    if (bid < 129) {
        const float4* src; int n4, rb, nb;
        if (bid < 64)       { src = (const float4*)W; n4 = N_DIM * N_DIM / 4; rb = bid;      nb = 64; }
        else if (bid < 128) { src = (const float4*)U; n4 = N_DIM * D_DIM / 4; rb = bid - 64; nb = 64; }
        else                { src = (const float4*)b; n4 = N_DIM / 4;         rb = 0;        nb = 1;  }
        float mv = 0.0f;
        for (int i = rb * 256 + t; i < n4; i += nb * 256) {
            float4 v = src[i];
            mv = fmaxf(mv, fmaxf(fmaxf(fabsf(v.x), fabsf(v.y)), fmaxf(fabsf(v.z), fabsf(v.w))));
        }
#pragma unroll
        for (int s = 1; s < 64; s <<= 1) mv = fmaxf(mv, __shfl_xor(mv, s));
        float* ls = (float*)sacc;
        if (lane == 0) ls[wave] = mv;
        __syncthreads();
        if (t == 0) {
            float mm = fmaxf(fmaxf(ls[0], ls[1]), fmaxf(ls[2], ls[3]));
            float* part = (bid < 64) ? pW : (bid < 128 ? pU : pB);
            int    rbb  = (bid < 64) ? bid : (bid < 128 ? bid - 64 : 0);
            int*   cnt  = (bid < 64) ? cntW : (bid < 128 ? cntU : cntB);
            __hip_atomic_store(&part[rbb], mm, __ATOMIC_RELAXED, __HIP_MEMORY_SCOPE_AGENT);
            __hip_atomic_fetch_add(cnt, 1, __ATOMIC_RELEASE, __HIP_MEMORY_SCOPE_AGENT);
        }
    }

    // ---------- region barrier: read-only polls, local reduce ----------
    if (t == 0) {
        if (bid < 256) {
            while (__hip_atomic_load(cntW, __ATOMIC_ACQUIRE, __HIP_MEMORY_SCOPE_AGENT) < 64)
                __builtin_amdgcn_s_sleep(2);
            float m = 0.0f;
#pragma unroll 16
            for (int i = 0; i < 64; ++i)
                m = fmaxf(m, __hip_atomic_load(&pW[i], __ATOMIC_RELAXED, __HIP_MEMORY_SCOPE_AGENT));
            smax[0] = m;
            if (bid == 0) fin[0] = m;   // published for solve (kernel boundary)
        } else {
            while (__hip_atomic_load(cntU, __ATOMIC_ACQUIRE, __HIP_MEMORY_SCOPE_AGENT) < 64)
                __builtin_amdgcn_s_sleep(2);
            while (__hip_atomic_load(cntB, __ATOMIC_ACQUIRE, __HIP_MEMORY_SCOPE_AGENT) < 1)
                __builtin_amdgcn_s_sleep(2);
            float mu = 0.0f;
#pragma unroll 16
            for (int i = 0; i < 64; ++i)
                mu = fmaxf(mu, __hip_atomic_load(&pU[i], __ATOMIC_RELAXED, __HIP_MEMORY_SCOPE_AGENT));
            smax[1] = mu;
            smax[2] = __hip_atomic_load(&pB[0], __ATOMIC_RELAXED, __HIP_MEMORY_SCOPE_AGENT);
        }
    }
    __syncthreads();

    // ---------- phase 2 ----------
    if (bid < 256) {
        // ---- W quant (2 rows per block) ----
        const float s = smax[0] * (1.0f / QMAX);
        const float inv = 1.0f / s;
        int idx = bid * 256 + t;                   // float4 index into W
        float4 w = ((const float4*)W)[idx];
        int k = (idx << 2) & (N_DIM - 1);
        int r = (idx << 2) >> 9;
        char4 c;
        c.x = (signed char)(int)rintf(w.x * inv);
        c.y = (signed char)(int)rintf(w.y * inv);
        c.z = (signed char)(int)rintf(w.z * inv);
        c.w = (signed char)(int)rintf(w.w * inv);
        int kc = k >> 6, q = (k >> 4) & 3, jj = k & 15;
        *(char4*)&Qp8[((kc << 9) + r) * 64 + q * 16 + jj] = c;
    } else {
        // ---- UxT[c][i] = bq[i] + sU * sum_d Qu[i][d]*x[c][d] ----
        const float sU = smax[1] * (1.0f / QMAX);
        const float invU = 1.0f / sU;
        const float sb = smax[2] * (1.0f / QMAX);
        const int bx = bid - 256;                  // 0..255
        const int i0 = (bx >> 3) * 16;             // U-row tile base (32 groups)
        const int c0 = (bx & 7) * 16;              // batch-col tile base (8 groups)
        // vectorized x staging: hi/lo bf16 split, float4 loads
        for (int i = t; i < 16 * 196; i += 256) {
            int r = i / 196, kf = i - r * 196;
            float4 v = *(const float4*)&x[(c0 + r) * D_DIM + (kf << 2)];
            union { __bf16 e[4]; ushort4 u; } hh, ll;
            float f0 = v.x, f1 = v.y, f2 = v.z, f3 = v.w;
            __bf16 h0 = (__bf16)f0, h1 = (__bf16)f1, h2 = (__bf16)f2, h3 = (__bf16)f3;
            hh.e[0] = h0; hh.e[1] = h1; hh.e[2] = h2; hh.e[3] = h3;
            ll.e[0] = (__bf16)(f0 - (float)h0);
            ll.e[1] = (__bf16)(f1 - (float)h1);
            ll.e[2] = (__bf16)(f2 - (float)h2);
            ll.e[3] = (__bf16)(f3 - (float)h3);
            *(ushort4*)&xhS[r][kf << 2] = hh.u;
            *(ushort4*)&xlS[r][kf << 2] = ll.u;
        }
        // zero-fill pad k in [784, 800)
        {
            int r = t >> 4, k = D_DIM + (t & 15);
            xhS[r][k] = (__bf16)0.0f; xlS[r][k] = (__bf16)0.0f;
        }
        __syncthreads();
        const int m = lane & 15, quad = lane >> 4;
        f32x4 acc = {};
        for (int kc = wave; kc < 25; kc += 4) {
            const int k0 = (kc << 5) + (quad << 3);
            bf16x8 au = {};
            if (k0 < D_DIM) {   // kc==24 only quads 0,1 valid (784 = 24*32+16)
                const float4 u0 = *(const float4*)&U[(i0 + m) * D_DIM + k0];
                const float4 u1 = *(const float4*)&U[(i0 + m) * D_DIM + k0 + 4];
                au[0] = (__bf16)rintf(u0.x * invU); au[1] = (__bf16)rintf(u0.y * invU);
                au[2] = (__bf16)rintf(u0.z * invU); au[3] = (__bf16)rintf(u0.w * invU);
                au[4] = (__bf16)rintf(u1.x * invU); au[5] = (__bf16)rintf(u1.y * invU);
                au[6] = (__bf16)rintf(u1.z * invU); au[7] = (__bf16)rintf(u1.w * invU);
            }
            bf16x8 bh = *(const bf16x8*)&xhS[m][k0];
            bf16x8 bl = *(const bf16x8*)&xlS[m][k0];
            acc = __builtin_amdgcn_mfma_f32_16x16x32_bf16(au, bh, acc, 0, 0, 0);
            acc = __builtin_amdgcn_mfma_f32_16x16x32_bf16(au, bl, acc, 0, 0, 0);
        }
        sacc[wave][lane] = acc;
        __syncthreads();
        if (wave == 0) {
            f32x4 s0 = sacc[0][lane], s1 = sacc[1][lane];
            f32x4 s2 = sacc[2][lane], s3 = sacc[3][lane];
            const int row0 = i0 + (quad << 2);
            f32x4 o;
#pragma unroll
            for (int r = 0; r < 4; ++r)
                o[r] = sU * (s0[r] + s1[r] + s2[r] + s3[r])
                     + rintf(b[row0 + r] / sb) * sb;
            *(f32x4*)&UxT[(c0 + m) * N_DIM + row0] = o;
        }
    }
}

// ---------------- fused int8-MFMA solve + logits (16 waves) ----------------
__global__ __launch_bounds__(1024, 1) void solve_kernel(const signed char* __restrict__ Qp8,
                                                        const float* __restrict__ UxT,
                                                        const float* __restrict__ wsf,
                                                        const float* __restrict__ Wc,
                                                        const float* __restrict__ bc,
                                                        float* __restrict__ out) {
    __shared__ signed char zh[2][16][ZPITCH];
    __shared__ signed char zl[2][16][ZPITCH];
    __shared__ float red[16][16][C_DIM];
    const int t = threadIdx.x;
    const int wave = t >> 6;      // 0..15
    const int lane = t & 63;
    const int m = lane & 15;      // batch col within block tile
    const int quad = lane >> 4;   // D-row group
    const int c0 = blockIdx.x * 16;
    const float sW = wsf[WS_FIN] * (1.0f / QMAX);  // max|W| published by prep
    const float c1 = sW * (1.0f / 2048.0f);
    const float hc_hi = c1 * 128.0f;     // original-units constants
    const float g_hi = sW * 128.0f;      // = hc_hi * 2048 (exact)
    const float g_lo = sW * 0.5f;        // = hc_lo * 2048 (exact)
    const int rowbase = wave * 32;

    // register-resident A fragments: 8 kc x 2 M-tiles x 16B
    i32x4 A[MT][8];
#pragma unroll
    for (int ti = 0; ti < MT; ++ti)
#pragma unroll
        for (int kc = 0; kc < 8; ++kc)
            A[ti][kc] = *(const i32x4*)&Qp8[((kc << 9) + rowbase + ti * 16 + m) * 64 + (quad << 4)];

    // rowsum(Q) per row via ones-vector i8 MFMA (exact int; layout matches C)
    const i32x4 onesb = {0x01010101, 0x01010101, 0x01010101, 0x01010101};
    i32x4 rs[MT];
#pragma unroll
    for (int ti = 0; ti < MT; ++ti) {
        i32x4 a = {};
#pragma unroll
        for (int kc = 0; kc < 8; ++kc)
            a = __builtin_amdgcn_mfma_i32_16x16x64_i8(A[ti][kc], onesb, a, 0, 0, 0);
        rs[ti] = a;
    }

    // prologue. Scaled units: Z = 2048*z (exact 2^11 scaling, bit-identical
    // trajectory), UX2 = 2048*uxh.
    float Z[MT][4];
    float UX2[MT][4];
#pragma unroll
    for (int ti = 0; ti < MT; ++ti) {
        const int row0 = rowbase + ti * 16 + (quad << 2);
        const f32x4 v4 = *(const f32x4*)&UxT[(c0 + m) * N_DIM + row0];
        int vq[4];
#pragma unroll
        for (int r = 0; r < 4; ++r) {
            const float v = v4[r];
            const float uxh = 0.5f * (v + hc_hi * (float)rs[ti][r]);
            UX2[ti][r] = uxh * 2048.0f;
            const float z1 = fmaxf(0.5f * v, 0.0f);
            const float Z1 = z1 * 2048.0f;
            Z[ti][r] = Z1;
            vq[r] = (int)rintf(Z1);
        }
        unsigned int h, l;
        pack_hl(vq, h, l);
        *(unsigned int*)&zh[0][m][row0] = h;
        *(unsigned int*)&zl[0][m][row0] = l;
    }

#pragma unroll
    for (int ti = 0; ti < MT; ++ti)
#pragma unroll
        for (int kc = 0; kc < 8; ++kc)
            asm volatile("" : "+v"(A[ti][kc]));
    __syncthreads();

    int cur = 0;
    for (int it = 1; it < N_ITERS; ++it) {
        const bool lo = (it >= HILO_START);
        const bool wlo = (it >= HILO_START - 1);
        i32x4 acch[MT] = {};
        i32x4 accl[MT] = {};
        if (lo) {
#pragma unroll
            for (int kc = 0; kc < 8; ++kc) {
                i32x4 bh = *(const i32x4*)&zh[cur][m][(kc << 6) + (quad << 4)];
                i32x4 bl = *(const i32x4*)&zl[cur][m][(kc << 6) + (quad << 4)];
#pragma unroll
                for (int ti = 0; ti < MT; ++ti) {
                    acch[ti] = __builtin_amdgcn_mfma_i32_16x16x64_i8(A[ti][kc], bh, acch[ti], 0, 0, 0);
                    accl[ti] = __builtin_amdgcn_mfma_i32_16x16x64_i8(A[ti][kc], bl, accl[ti], 0, 0, 0);
                }
            }
        } else {
#pragma unroll
            for (int kc = 0; kc < 8; ++kc) {
                i32x4 bh = *(const i32x4*)&zh[cur][m][(kc << 6) + (quad << 4)];
#pragma unroll
                for (int ti = 0; ti < MT; ++ti)
                    acch[ti] = __builtin_amdgcn_mfma_i32_16x16x64_i8(A[ti][kc], bh, acch[ti], 0, 0, 0);
            }
        }
        const int nxt = cur ^ 1;
#pragma unroll
        for (int ti = 0; ti < MT; ++ti) {
            const int row0 = rowbase + ti * 16 + (quad << 2);
            int vq[4];
#pragma unroll
            for (int r = 0; r < 4; ++r) {
                float base = fmaf(0.5f, Z[ti][r], UX2[ti][r]);
                float u = lo ? fmaf(g_hi, (float)acch[ti][r], fmaf(g_lo, (float)accl[ti][r], base))
                             : fmaf(g_hi, (float)acch[ti][r], base);
                float Zn = fmaxf(u, 0.0f);
                Z[ti][r] = Zn;
                vq[r] = (int)rintf(Zn);
            }
            unsigned int h, l;
            pack_hl(vq, h, l);
            *(unsigned int*)&zh[nxt][m][row0] = h;
            if (wlo) *(unsigned int*)&zl[nxt][m][row0] = l;
        }
        __syncthreads();
        cur = nxt;
    }

    // ---- fused logits from register z (shfl-first reduction) ----
    {
        float p[C_DIM];
#pragma unroll
        for (int cl = 0; cl < C_DIM; ++cl) p[cl] = 0.0f;
#pragma unroll
        for (int ti = 0; ti < MT; ++ti) {
            const int row0 = rowbase + ti * 16 + (quad << 2);
#pragma unroll
            for (int r = 0; r < 4; ++r) {
                float zv = Z[ti][r] * (1.0f / 2048.0f);
#pragma unroll
                for (int cl = 0; cl < C_DIM; ++cl)
                    p[cl] += zv * Wc[cl * N_DIM + row0 + r];
            }
        }
#pragma unroll
        for (int cl = 0; cl < C_DIM; ++cl) {
            p[cl] += __shfl_xor(p[cl], 16);
            p[cl] += __shfl_xor(p[cl], 32);
        }
        if (lane < 16) {
#pragma unroll
            for (int cl = 0; cl < C_DIM; ++cl) red[wave][lane][cl] = p[cl];
        }
        __syncthreads();
        for (int s = 8; s > 0; s >>= 1) {
            if (wave < s && lane < 16) {
#pragma unroll
                for (int cl = 0; cl < C_DIM; ++cl)
                    red[wave][lane][cl] += red[wave + s][lane][cl];
            }
            __syncthreads();
        }
        if (t < 16 * C_DIM) {
            int col = t & 15;
            int cl  = t >> 4;
            out[(c0 + col) * C_DIM + cl] = red[0][col][cl] + bc[cl];
        }
    }
}

extern "C" void kernel_launch(void* const* d_in, const int* in_sizes, int n_in,
                              void* d_out, int out_size, void* d_ws, size_t ws_size,
                              hipStream_t stream) {
    const float* W  = (const float*)d_in[0];
    const float* U  = (const float*)d_in[1];
    const float* b  = (const float*)d_in[2];
    const float* x  = (const float*)d_in[3];
    const float* Wc = (const float*)d_in[4];
    const float* bc = (const float*)d_in[5];
    float* out = (float*)d_out;

    float* ws = (float*)d_ws;
    int* sync = (int*)ws;                               // counters/finals/partials
    signed char* Qp8 = (signed char*)(ws + 256);        // 512x512 int8, [kc][r][64B]
    float* UxT = ws + 256 + (N_DIM * N_DIM / 4);        // 128x512 fp32

    hipMemsetAsync(sync, 0, 320, stream);               // counters + finals only
    prep_kernel<<<512, 256, 0, stream>>>(W, U, b, x, sync, Qp8, UxT);
    solve_kernel<<<8, 1024, 0, stream>>>(Qp8, UxT, ws, Wc, bc, out);
}

// Round 4
// 142.392 us; speedup vs baseline: 1.1368x; 1.0873x over previous
//
#include <hip/hip_runtime.h>
#include <hip/hip_bf16.h>

// QuantisedMonDEQ: n=512, d=784, B=128, C=10. All inputs/outputs float32.
// z_{t+1} = relu(0.5 z + 0.5 (Wq z + Ux)), 40 iters; logits = z*^T Wc^T + bc.
//
// INT8 formulation: Wq = sW*Q, Q = rint(W/sW) exact int8. z held as Q4.11
// fixed point v (int16), split v = 256*zh + (zlm+128), zh,zlm int8.
//   Q.v = 256*(Q.zh) + Q.zlm + 128*rowsum(Q)   (rowsum folded into Ux).
// Iters 1..27: hi-plane only; iters 28..39 both planes. Z (= 2048*z, fp32,
// bit-exact power-of-two scaling) + Ux fold live in registers per lane; LDS
// carries only the int8 B-plane transpose. Rowsum via ones-vector i8 MFMA.
// Pack: v_cvt_pk_i16_i32 (saturating) + v_perm_b32.
//
// Round-4 structure (post-mortem r2/r3): device-scope spin barriers cost
// ~20-25us on 8 XCDs regardless of RMW contention -> back to separate
// dispatches (kernel boundary is cheaper). No atomics, no memset: maxes go
// to per-block partial slots, consumers reduce 64 partials locally; every
// ws cell is fully rewritten each replay (re-poison safe).
//   scales: W/U partial maxes; b max+quant (bq); x -> xh/xl bf16 planes
//           (scale-independent precompute).
//   prep:   blocks 0..255 quantize W (int8, MFMA-fragment layout);
//           blocks 256..287: one per 16-row U-slice, quantize U rows ONCE
//           into padded LDS, sweep all 8 batch-col groups with B-fragments
//           loaded straight from xh/xl (no per-block x conversion, no
//           kc-guard: tails zero-padded).
//   solve:  unchanged (sW via pscale64 over the W partials).

#define N_DIM 512
#define D_DIM 784
#define B_DIM 128
#define C_DIM 10
#define QMAX 127.0f
#define N_ITERS 40
#define HILO_START 28
#define ZPITCH 528     // bytes per column plane row; 16B-aligned
#define MT 2           // 16-row M-tiles per wave (16 waves x 32 rows = 512)
#define XPITCH 800     // bf16 elems per x row in ws (784 data + 16 zero pad)
#define QUPITCH 808    // bf16 elems per U row in LDS (pad spreads banks)

typedef int    i32x4  __attribute__((ext_vector_type(4)));
typedef float  f32x4  __attribute__((ext_vector_type(4)));
typedef __bf16 bf16x8 __attribute__((ext_vector_type(8)));
typedef short  s16x2  __attribute__((ext_vector_type(2)));

// ws float offsets
#define WSF_PW  0                    // 64 W partial maxes
#define WSF_PU  64                   // 64 U partial maxes
#define WSF_SB  128                  // sb scalar
#define WSF_BQ  192                  // bq[512] fp32
#define WSF_XH  704                  // xh bf16 [128][XPITCH] = 51200 floats
#define WSF_XL  (WSF_XH + 51200)     // xl bf16 [128][XPITCH]
#define WSF_QP8 (WSF_XL + 51200)     // Qp8 int8 512x512 = 65536 floats
#define WSF_UXT (WSF_QP8 + 65536)    // UxT fp32 [128][512]

__device__ __forceinline__ float pscale64(const float* __restrict__ p) {
    float m = 0.0f;
#pragma unroll 16
    for (int i = 0; i < 64; ++i) m = fmaxf(m, p[i]);
    return m * (1.0f / QMAX);
}

// vq[0..3] (>=0) -> saturate to i16, h = hi bytes, l = lo bytes ^ 0x80.
__device__ __forceinline__ void pack_hl(const int vq[4], unsigned int& h, unsigned int& l) {
    int pk01, pk23;
#if __has_builtin(__builtin_amdgcn_cvt_pk_i16)
    union { s16x2 v; int i; } u0, u1;
    u0.v = __builtin_amdgcn_cvt_pk_i16(vq[0], vq[1]);
    u1.v = __builtin_amdgcn_cvt_pk_i16(vq[2], vq[3]);
    pk01 = u0.i; pk23 = u1.i;
#else
    asm("v_cvt_pk_i16_i32 %0, %1, %2" : "=v"(pk01) : "v"(vq[0]), "v"(vq[1]));
    asm("v_cvt_pk_i16_i32 %0, %1, %2" : "=v"(pk23) : "v"(vq[2]), "v"(vq[3]));
#endif
    h = __builtin_amdgcn_perm((unsigned int)pk23, (unsigned int)pk01, 0x07050301u);
    l = __builtin_amdgcn_perm((unsigned int)pk23, (unsigned int)pk01, 0x06040200u) ^ 0x80808080u;
}

// ---- scales: blocks 0..63 W-max, 64..127 U-max, 128 b-max+quant,
// ---- 129..192 x -> xh/xl bf16 split ----
__global__ __launch_bounds__(256) void scales_kernel(const float* __restrict__ W,
                                                     const float* __restrict__ U,
                                                     const float* __restrict__ b,
                                                     const float* __restrict__ x,
                                                     float* __restrict__ ws) {
    __shared__ float ls[4];
    __shared__ float sbS;
    const int t = threadIdx.x, wave = t >> 6, lane = t & 63;
    const int bid = blockIdx.x;
    if (bid < 128) {
        const float4* src; int n4, rb;
        if (bid < 64) { src = (const float4*)W; n4 = N_DIM * N_DIM / 4; rb = bid; }
        else          { src = (const float4*)U; n4 = N_DIM * D_DIM / 4; rb = bid - 64; }
        float mv = 0.0f;
        for (int i = rb * 256 + t; i < n4; i += 64 * 256) {
            float4 v = src[i];
            mv = fmaxf(mv, fmaxf(fmaxf(fabsf(v.x), fabsf(v.y)), fmaxf(fabsf(v.z), fabsf(v.w))));
        }
#pragma unroll
        for (int s = 1; s < 64; s <<= 1) mv = fmaxf(mv, __shfl_xor(mv, s));
        if (lane == 0) ls[wave] = mv;
        __syncthreads();
        if (t == 0) ws[bid] = fmaxf(fmaxf(ls[0], ls[1]), fmaxf(ls[2], ls[3]));
    } else if (bid == 128) {
        // b: block-local max + quantize bq = rint(b/sb)*sb
        float4 v = {0.0f, 0.0f, 0.0f, 0.0f};
        if (t < N_DIM / 4) v = ((const float4*)b)[t];
        float mv = fmaxf(fmaxf(fabsf(v.x), fabsf(v.y)), fmaxf(fabsf(v.z), fabsf(v.w)));
#pragma unroll
        for (int s = 1; s < 64; s <<= 1) mv = fmaxf(mv, __shfl_xor(mv, s));
        if (lane == 0) ls[wave] = mv;
        __syncthreads();
        if (t == 0) {
            float m = fmaxf(fmaxf(ls[0], ls[1]), fmaxf(ls[2], ls[3]));
            float sb = m * (1.0f / QMAX);
            ws[WSF_SB] = sb;
            sbS = sb;
        }
        __syncthreads();
        if (t < N_DIM / 4) {
            const float sb = sbS;
            float4 o;
            o.x = rintf(v.x / sb) * sb;
            o.y = rintf(v.y / sb) * sb;
            o.z = rintf(v.z / sb) * sb;
            o.w = rintf(v.w / sb) * sb;
            ((float4*)(ws + WSF_BQ))[t] = o;
        }
    } else {
        // xsplit: 64 blocks over 128x196 float4s
        __bf16* xh = (__bf16*)(ws + WSF_XH);
        __bf16* xl = (__bf16*)(ws + WSF_XL);
        const int xb = bid - 129;
        for (int i = xb * 256 + t; i < 128 * 196; i += 64 * 256) {
            int r = i / 196, kf = i - r * 196;
            float4 v = *(const float4*)&x[r * D_DIM + (kf << 2)];
            union { __bf16 e[4]; ushort4 u; } hh, ll;
            __bf16 h0 = (__bf16)v.x, h1 = (__bf16)v.y, h2 = (__bf16)v.z, h3 = (__bf16)v.w;
            hh.e[0] = h0; hh.e[1] = h1; hh.e[2] = h2; hh.e[3] = h3;
            ll.e[0] = (__bf16)(v.x - (float)h0);
            ll.e[1] = (__bf16)(v.y - (float)h1);
            ll.e[2] = (__bf16)(v.z - (float)h2);
            ll.e[3] = (__bf16)(v.w - (float)h3);
            *(ushort4*)&xh[r * XPITCH + (kf << 2)] = hh.u;
            *(ushort4*)&xl[r * XPITCH + (kf << 2)] = ll.u;
        }
        if (xb == 0) {
            // zero pad cols [784,800) for all 128 rows (8 bf16 per thread)
            int r = t >> 1, c = D_DIM + (t & 1) * 8;
            ushort4 z = {0, 0, 0, 0};
            *(ushort4*)&xh[r * XPITCH + c] = z; *(ushort4*)&xh[r * XPITCH + c + 4] = z;
            *(ushort4*)&xl[r * XPITCH + c] = z; *(ushort4*)&xl[r * XPITCH + c + 4] = z;
        }
    }
}

// ---- prep: blocks 0..255 quantW(int8); 256..287 UxT (16-row U-slices) ----
__global__ __launch_bounds__(256) void prep_kernel(const float* __restrict__ W,
                                                   const float* __restrict__ U,
                                                   float* __restrict__ ws,
                                                   signed char* __restrict__ Qp8) {
    __shared__ __bf16 quS[16][QUPITCH];
    const int t = threadIdx.x;
    const int wave = t >> 6, lane = t & 63;
    const int bid = blockIdx.x;
    if (bid < 256) {
        // ---- W quant (2 rows per block) ----
        const float s = pscale64(ws + WSF_PW);
        const float inv = 1.0f / s;
        int idx = bid * 256 + t;                   // float4 index into W
        float4 w = ((const float4*)W)[idx];
        int k = (idx << 2) & (N_DIM - 1);
        int r = (idx << 2) >> 9;
        char4 c;
        c.x = (signed char)(int)rintf(w.x * inv);
        c.y = (signed char)(int)rintf(w.y * inv);
        c.z = (signed char)(int)rintf(w.z * inv);
        c.w = (signed char)(int)rintf(w.w * inv);
        int kc = k >> 6, q = (k >> 4) & 3, jj = k & 15;
        *(char4*)&Qp8[((kc << 9) + r) * 64 + q * 16 + jj] = c;
    } else {
        // ---- UxT rows [i0, i0+16): quantize U-slice once, sweep 8 cgroups ----
        const float sU = pscale64(ws + WSF_PU);
        const float invU = 1.0f / sU;
        const int i0 = (bid - 256) * 16;
        for (int i = t; i < 16 * 196; i += 256) {
            int r = i / 196, kf = i - r * 196;
            float4 v = *(const float4*)&U[(i0 + r) * D_DIM + (kf << 2)];
            union { __bf16 e[4]; ushort4 u; } q;
            q.e[0] = (__bf16)rintf(v.x * invU);
            q.e[1] = (__bf16)rintf(v.y * invU);
            q.e[2] = (__bf16)rintf(v.z * invU);
            q.e[3] = (__bf16)rintf(v.w * invU);
            *(ushort4*)&quS[r][kf << 2] = q.u;
        }
        { int r = t >> 4, k = D_DIM + (t & 15); quS[r][k] = (__bf16)0.0f; }
        __syncthreads();
        const int m = lane & 15, quad = lane >> 4;
        const __bf16* xh = (const __bf16*)(ws + WSF_XH);
        const __bf16* xl = (const __bf16*)(ws + WSF_XL);
        const float* bq = ws + WSF_BQ;
        float* UxT = ws + WSF_UXT;
        const int row0 = i0 + (quad << 2);
        const f32x4 bqv = *(const f32x4*)&bq[row0];
        for (int cg = wave; cg < 8; cg += 4) {
            const __bf16* xhr = &xh[(cg * 16 + m) * XPITCH];
            const __bf16* xlr = &xl[(cg * 16 + m) * XPITCH];
            f32x4 acc = {};
#pragma unroll 5
            for (int kc = 0; kc < 25; ++kc) {
                bf16x8 au = *(const bf16x8*)&quS[m][kc * 32 + (quad << 3)];
                bf16x8 bh = *(const bf16x8*)&xhr[kc * 32 + (quad << 3)];
                bf16x8 bl = *(const bf16x8*)&xlr[kc * 32 + (quad << 3)];
                acc = __builtin_amdgcn_mfma_f32_16x16x32_bf16(au, bh, acc, 0, 0, 0);
                acc = __builtin_amdgcn_mfma_f32_16x16x32_bf16(au, bl, acc, 0, 0, 0);
            }
            f32x4 o;
#pragma unroll
            for (int r = 0; r < 4; ++r) o[r] = sU * acc[r] + bqv[r];
            *(f32x4*)&UxT[(cg * 16 + m) * N_DIM + row0] = o;
        }
    }
}

// ---------------- fused int8-MFMA solve + logits (16 waves) ----------------
__global__ __launch_bounds__(1024, 1) void solve_kernel(const signed char* __restrict__ Qp8,
                                                        const float* __restrict__ UxT,
                                                        const float* __restrict__ wsf,
                                                        const float* __restrict__ Wc,
                                                        const float* __restrict__ bc,
                                                        float* __restrict__ out) {
    __shared__ signed char zh[2][16][ZPITCH];
    __shared__ signed char zl[2][16][ZPITCH];
    __shared__ float red[16][16][C_DIM];
    const int t = threadIdx.x;
    const int wave = t >> 6;      // 0..15
    const int lane = t & 63;
    const int m = lane & 15;      // batch col within block tile
    const int quad = lane >> 4;   // D-row group
    const int c0 = blockIdx.x * 16;
    const float sW = pscale64(wsf + WSF_PW);   // reduce W partials locally
    const float c1 = sW * (1.0f / 2048.0f);
    const float hc_hi = c1 * 128.0f;     // original-units constants
    const float g_hi = sW * 128.0f;      // = hc_hi * 2048 (exact)
    const float g_lo = sW * 0.5f;        // = hc_lo * 2048 (exact)
    const int rowbase = wave * 32;

    // register-resident A fragments: 8 kc x 2 M-tiles x 16B
    i32x4 A[MT][8];
#pragma unroll
    for (int ti = 0; ti < MT; ++ti)
#pragma unroll
        for (int kc = 0; kc < 8; ++kc)
            A[ti][kc] = *(const i32x4*)&Qp8[((kc << 9) + rowbase + ti * 16 + m) * 64 + (quad << 4)];

    // rowsum(Q) per row via ones-vector i8 MFMA (exact int; layout matches C)
    const i32x4 onesb = {0x01010101, 0x01010101, 0x01010101, 0x01010101};
    i32x4 rs[MT];
#pragma unroll
    for (int ti = 0; ti < MT; ++ti) {
        i32x4 a = {};
#pragma unroll
        for (int kc = 0; kc < 8; ++kc)
            a = __builtin_amdgcn_mfma_i32_16x16x64_i8(A[ti][kc], onesb, a, 0, 0, 0);
        rs[ti] = a;
    }

    // prologue. Scaled units: Z = 2048*z (exact 2^11 scaling, bit-identical
    // trajectory), UX2 = 2048*uxh.
    float Z[MT][4];
    float UX2[MT][4];
#pragma unroll
    for (int ti = 0; ti < MT; ++ti) {
        const int row0 = rowbase + ti * 16 + (quad << 2);
        const f32x4 v4 = *(const f32x4*)&UxT[(c0 + m) * N_DIM + row0];
        int vq[4];
#pragma unroll
        for (int r = 0; r < 4; ++r) {
            const float v = v4[r];
            const float uxh = 0.5f * (v + hc_hi * (float)rs[ti][r]);
            UX2[ti][r] = uxh * 2048.0f;
            const float z1 = fmaxf(0.5f * v, 0.0f);
            const float Z1 = z1 * 2048.0f;
            Z[ti][r] = Z1;
            vq[r] = (int)rintf(Z1);
        }
        unsigned int h, l;
        pack_hl(vq, h, l);
        *(unsigned int*)&zh[0][m][row0] = h;
        *(unsigned int*)&zl[0][m][row0] = l;
    }

#pragma unroll
    for (int ti = 0; ti < MT; ++ti)
#pragma unroll
        for (int kc = 0; kc < 8; ++kc)
            asm volatile("" : "+v"(A[ti][kc]));
    __syncthreads();

    int cur = 0;
    for (int it = 1; it < N_ITERS; ++it) {
        const bool lo = (it >= HILO_START);
        const bool wlo = (it >= HILO_START - 1);
        i32x4 acch[MT] = {};
        i32x4 accl[MT] = {};
        if (lo) {
#pragma unroll
            for (int kc = 0; kc < 8; ++kc) {
                i32x4 bh = *(const i32x4*)&zh[cur][m][(kc << 6) + (quad << 4)];
                i32x4 bl = *(const i32x4*)&zl[cur][m][(kc << 6) + (quad << 4)];
#pragma unroll
                for (int ti = 0; ti < MT; ++ti) {
                    acch[ti] = __builtin_amdgcn_mfma_i32_16x16x64_i8(A[ti][kc], bh, acch[ti], 0, 0, 0);
                    accl[ti] = __builtin_amdgcn_mfma_i32_16x16x64_i8(A[ti][kc], bl, accl[ti], 0, 0, 0);
                }
            }
        } else {
#pragma unroll
            for (int kc = 0; kc < 8; ++kc) {
                i32x4 bh = *(const i32x4*)&zh[cur][m][(kc << 6) + (quad << 4)];
#pragma unroll
                for (int ti = 0; ti < MT; ++ti)
                    acch[ti] = __builtin_amdgcn_mfma_i32_16x16x64_i8(A[ti][kc], bh, acch[ti], 0, 0, 0);
            }
        }
        const int nxt = cur ^ 1;
#pragma unroll
        for (int ti = 0; ti < MT; ++ti) {
            const int row0 = rowbase + ti * 16 + (quad << 2);
            int vq[4];
#pragma unroll
            for (int r = 0; r < 4; ++r) {
                float base = fmaf(0.5f, Z[ti][r], UX2[ti][r]);
                float u = lo ? fmaf(g_hi, (float)acch[ti][r], fmaf(g_lo, (float)accl[ti][r], base))
                             : fmaf(g_hi, (float)acch[ti][r], base);
                float Zn = fmaxf(u, 0.0f);
                Z[ti][r] = Zn;
                vq[r] = (int)rintf(Zn);
            }
            unsigned int h, l;
            pack_hl(vq, h, l);
            *(unsigned int*)&zh[nxt][m][row0] = h;
            if (wlo) *(unsigned int*)&zl[nxt][m][row0] = l;
        }
        __syncthreads();
        cur = nxt;
    }

    // ---- fused logits from register z (shfl-first reduction) ----
    {
        float p[C_DIM];
#pragma unroll
        for (int cl = 0; cl < C_DIM; ++cl) p[cl] = 0.0f;
#pragma unroll
        for (int ti = 0; ti < MT; ++ti) {
            const int row0 = rowbase + ti * 16 + (quad << 2);
#pragma unroll
            for (int r = 0; r < 4; ++r) {
                float zv = Z[ti][r] * (1.0f / 2048.0f);
#pragma unroll
                for (int cl = 0; cl < C_DIM; ++cl)
                    p[cl] += zv * Wc[cl * N_DIM + row0 + r];
            }
        }
#pragma unroll
        for (int cl = 0; cl < C_DIM; ++cl) {
            p[cl] += __shfl_xor(p[cl], 16);
            p[cl] += __shfl_xor(p[cl], 32);
        }
        if (lane < 16) {
#pragma unroll
            for (int cl = 0; cl < C_DIM; ++cl) red[wave][lane][cl] = p[cl];
        }
        __syncthreads();
        for (int s = 8; s > 0; s >>= 1) {
            if (wave < s && lane < 16) {
#pragma unroll
                for (int cl = 0; cl < C_DIM; ++cl)
                    red[wave][lane][cl] += red[wave + s][lane][cl];
            }
            __syncthreads();
        }
        if (t < 16 * C_DIM) {
            int col = t & 15;
            int cl  = t >> 4;
            out[(c0 + col) * C_DIM + cl] = red[0][col][cl] + bc[cl];
        }
    }
}

extern "C" void kernel_launch(void* const* d_in, const int* in_sizes, int n_in,
                              void* d_out, int out_size, void* d_ws, size_t ws_size,
                              hipStream_t stream) {
    const float* W  = (const float*)d_in[0];
    const float* U  = (const float*)d_in[1];
    const float* b  = (const float*)d_in[2];
    const float* x  = (const float*)d_in[3];
    const float* Wc = (const float*)d_in[4];
    const float* bc = (const float*)d_in[5];
    float* out = (float*)d_out;

    float* ws = (float*)d_ws;
    signed char* Qp8 = (signed char*)(ws + WSF_QP8);
    float* UxT = ws + WSF_UXT;

    scales_kernel<<<193, 256, 0, stream>>>(W, U, b, x, ws);
    prep_kernel<<<288, 256, 0, stream>>>(W, U, ws, Qp8);
    solve_kernel<<<8, 1024, 0, stream>>>(Qp8, UxT, ws, Wc, bc, out);
}